// Round 1
// baseline (557.561 us; speedup 1.0000x reference)
//
#include <hip/hip_runtime.h>
#include <math.h>

#define B_ 32
#define H_ 112
#define W_ 112
#define C_ 192
#define NPOS (B_*H_*W_)      // 401408
#define C4 (C_/4)            // 48

// ---------------- Kernel 1: per-position channel mean + max ----------------
// One wave (64 lanes) per spatial position. Lanes 0..47 each load a float4.
__global__ __launch_bounds__(256) void reduce_kernel(const float* __restrict__ x,
                                                     float2* __restrict__ ws2) {
    const int wave = threadIdx.x >> 6;
    const int lane = threadIdx.x & 63;
    const int p = blockIdx.x * 4 + wave;   // grid sized exactly: NPOS/4 blocks

    const float4* xp = (const float4*)(x + (size_t)p * C_);
    float s = 0.0f;
    float m = -INFINITY;
    if (lane < C4) {
        float4 v = xp[lane];
        s = v.x + v.y + v.z + v.w;
        m = fmaxf(fmaxf(v.x, v.y), fmaxf(v.z, v.w));
    }
    // full-wave butterfly reduce (wave = 64 lanes)
    #pragma unroll
    for (int off = 32; off > 0; off >>= 1) {
        s += __shfl_xor(s, off);
        m = fmaxf(m, __shfl_xor(m, off));
    }
    if (lane == 0) {
        float2 r;
        r.x = s * (1.0f / (float)C_);
        r.y = m;
        ws2[p] = r;
    }
}

// ---------------- Kernel 2: 7x7 SAME conv over (avg,max) + sigmoid ----------
__global__ __launch_bounds__(256) void conv_kernel(const float2* __restrict__ ws2,
                                                   const float* __restrict__ w,
                                                   float* __restrict__ att) {
    __shared__ float sw[98];
    if (threadIdx.x < 98) sw[threadIdx.x] = w[threadIdx.x];
    __syncthreads();

    const int p = blockIdx.x * 256 + threadIdx.x;
    if (p >= NPOS) return;

    const int b  = p / (H_ * W_);
    const int r  = p - b * (H_ * W_);
    const int y  = r / W_;
    const int xx = r - y * W_;

    const float2* base = ws2 + (size_t)b * (H_ * W_);
    float acc = 0.0f;
    #pragma unroll
    for (int ky = 0; ky < 7; ++ky) {
        const int yy = y + ky - 3;
        if (yy < 0 || yy >= H_) continue;
        const float2* row = base + yy * W_;
        #pragma unroll
        for (int kx = 0; kx < 7; ++kx) {
            const int xc = xx + kx - 3;
            if (xc < 0 || xc >= W_) continue;
            float2 am = row[xc];
            acc = fmaf(am.x, sw[(ky * 7 + kx) * 2 + 0], acc);
            acc = fmaf(am.y, sw[(ky * 7 + kx) * 2 + 1], acc);
        }
    }
    att[p] = 1.0f / (1.0f + __expf(-acc));
}

// ---------------- Kernel 3: out = x * att (broadcast over C) ---------------
__global__ __launch_bounds__(256) void mul_kernel(const float* __restrict__ x,
                                                  const float* __restrict__ att,
                                                  float* __restrict__ out) {
    const unsigned i = blockIdx.x * 256u + threadIdx.x;  // float4 index, exact grid
    const float4* x4 = (const float4*)x;
    float4* o4 = (float4*)out;
    float4 v = x4[i];
    const float a = att[i / C4];
    v.x *= a; v.y *= a; v.z *= a; v.w *= a;
    o4[i] = v;
}

extern "C" void kernel_launch(void* const* d_in, const int* in_sizes, int n_in,
                              void* d_out, int out_size, void* d_ws, size_t ws_size,
                              hipStream_t stream) {
    const float* x = (const float*)d_in[0];
    const float* w = (const float*)d_in[1];
    float* out = (float*)d_out;

    float2* ws2 = (float2*)d_ws;                           // NPOS float2 = 3.2 MB
    float*  att = (float*)((char*)d_ws + (size_t)NPOS * sizeof(float2)); // 1.6 MB

    // Kernel 1: NPOS/4 blocks x 256 threads (4 waves, 1 position per wave)
    reduce_kernel<<<NPOS / 4, 256, 0, stream>>>(x, ws2);

    // Kernel 2: one thread per position
    conv_kernel<<<(NPOS + 255) / 256, 256, 0, stream>>>(ws2, w, att);

    // Kernel 3: one thread per float4 of x. Total float4 = NPOS*48, divisible by 256.
    mul_kernel<<<(NPOS * C4) / 256, 256, 0, stream>>>(x, att, out);
}